// Round 4
// baseline (473.929 us; speedup 1.0000x reference)
//
#include <hip/hip_runtime.h>
#include <hip/hip_bf16.h>
#include <math.h>

#define B_ 64
#define T_ 2048
#define D_ 512
#define A_ 128
#define CHUNK 64                 // tokens per block
#define NCHUNK (T_ / CHUNK)      // 32 chunks per batch

typedef __bf16 bf16x8 __attribute__((ext_vector_type(8)));
typedef float  f32x4  __attribute__((ext_vector_type(4)));

// ---------------- Kernel 0: W1 [512][128] fp32 -> W1T [128][512] bf16 ----------------
__global__ __launch_bounds__(256) void prep_kernel(
    const float* __restrict__ W1, __hip_bfloat16* __restrict__ W1T)
{
    int idx = blockIdx.x * 256 + threadIdx.x;   // 64K elements, grid 256
    int k = idx >> 7;          // 0..511
    int n = idx & 127;         // 0..127
    W1T[n * D_ + k] = __float2bfloat16(W1[idx]);
}

__device__ inline bf16x8 cvt8(float4 a, float4 b) {
    bf16x8 r;
    r[0] = (__bf16)a.x; r[1] = (__bf16)a.y; r[2] = (__bf16)a.z; r[3] = (__bf16)a.w;
    r[4] = (__bf16)b.x; r[5] = (__bf16)b.y; r[6] = (__bf16)b.z; r[7] = (__bf16)b.w;
    return r;
}

__device__ inline float fast_tanh(float v) {
    v = fminf(fmaxf(v, -15.f), 15.f);
    float e = __expf(2.f * v);
    return (e - 1.f) / (e + 1.f);
}

// ---------------- Kernel 1: fused scores + unnormalized exp-pooling ----------------
// Block = 256 thr (4 waves), 64 tokens. Phase 1: each wave computes scores for its
// 16 tokens via MFMA (A = W1T rows from L2, B = x tokens converted to bf16).
// Phase 2: all 256 threads re-read the block's x tile (L2-hot) and accumulate
// e·x and e·x^2; partials + partial Z go to workspace.
__global__ __launch_bounds__(256) void fused_kernel(
    const float* __restrict__ x, const __hip_bfloat16* __restrict__ W1T_,
    const float* __restrict__ b1, const float* __restrict__ W2,
    const float* __restrict__ b2,
    float* __restrict__ pmu, float* __restrict__ pm2, float* __restrict__ pz)
{
    const __bf16* W1T = (const __bf16*)W1T_;
    const int tid  = threadIdx.x;
    const int wave = tid >> 6;
    const int lane = tid & 63;
    const int col  = lane & 15;    // token within wave's 16 / A row select
    const int kgrp = lane >> 4;    // 0..3

    const int  blk = blockIdx.x;
    const long tokbase = (long)blk * CHUNK + wave * 16;

    f32x4 acc[8];
#pragma unroll
    for (int mt = 0; mt < 8; mt++) acc[mt] = (f32x4){0.f, 0.f, 0.f, 0.f};

    const float* xp = x + (tokbase + col) * D_;
    const __bf16* wp = W1T + (long)col * D_;

#pragma unroll 4
    for (int ks = 0; ks < 16; ks++) {
        const int klane = ks * 32 + kgrp * 8;
        float4 a0 = *(const float4*)(xp + klane);
        float4 a1 = *(const float4*)(xp + klane + 4);
        bf16x8 bf = cvt8(a0, a1);
#pragma unroll
        for (int mt = 0; mt < 8; mt++) {
            bf16x8 af = *(const bf16x8*)(wp + (long)mt * 16 * D_ + klane);
            acc[mt] = __builtin_amdgcn_mfma_f32_16x16x32_bf16(af, bf, acc[mt], 0, 0, 0);
        }
    }

    // epilogue: n = mt*16 + kgrp*4 + r ; token (local) = wave*16 + col
    float p = 0.f;
#pragma unroll
    for (int mt = 0; mt < 8; mt++) {
#pragma unroll
        for (int r = 0; r < 4; r++) {
            int n = mt * 16 + kgrp * 4 + r;
            p += fast_tanh(acc[mt][r] + b1[n]) * W2[n];
        }
    }
    p += __shfl_xor(p, 16, 64);
    p += __shfl_xor(p, 32, 64);

    __shared__ float se[CHUNK];
    if (lane < 16)
        se[wave * 16 + col] = __expf(p + b2[0]);   // |s|<=11.4: no max needed in fp32
    __syncthreads();

    // ---- phase 2: pooling over the block's 64 tokens (x re-read is L2-hot) ----
    const int tg = tid >> 7;          // 0/1
    const int dq = tid & 127;         // float4 slot over D=512
    const float* xb = x + (long)blk * CHUNK * D_ + dq * 4;

    float4 mu = {0.f, 0.f, 0.f, 0.f};
    float4 m2 = {0.f, 0.f, 0.f, 0.f};
#pragma unroll 4
    for (int t = tg; t < CHUNK; t += 2) {
        float e = se[t];
        float4 xv = *(const float4*)(xb + (long)t * D_);
        mu.x = fmaf(e, xv.x, mu.x);
        mu.y = fmaf(e, xv.y, mu.y);
        mu.z = fmaf(e, xv.z, mu.z);
        mu.w = fmaf(e, xv.w, mu.w);
        m2.x = fmaf(e * xv.x, xv.x, m2.x);
        m2.y = fmaf(e * xv.y, xv.y, m2.y);
        m2.z = fmaf(e * xv.z, xv.z, m2.z);
        m2.w = fmaf(e * xv.w, xv.w, m2.w);
    }

    __shared__ float4 smu[256];
    __shared__ float4 sm2[256];
    smu[tid] = mu;
    sm2[tid] = m2;
    __syncthreads();

    if (tid < 128) {
        float4 a = smu[tid], c = smu[tid + 128];
        float4 e = sm2[tid], f = sm2[tid + 128];
        a.x += c.x; a.y += c.y; a.z += c.z; a.w += c.w;
        e.x += f.x; e.y += f.y; e.z += f.z; e.w += f.w;
        *(float4*)(pmu + (long)blk * D_ + dq * 4) = a;
        *(float4*)(pm2 + (long)blk * D_ + dq * 4) = e;
    }
    if (tid == 0) {
        float z = 0.f;
#pragma unroll
        for (int t = 0; t < CHUNK; t++) z += se[t];
        pz[blk] = z;
    }
}

// ---------------- Kernel 2: finalize — reduce 32 chunk-partials, normalize ----------------
__global__ __launch_bounds__(256) void finalize_kernel(
    const float* __restrict__ pmu, const float* __restrict__ pm2,
    const float* __restrict__ pz, float* __restrict__ out)
{
    const int b = blockIdx.x;
    const int tid = threadIdx.x;

    __shared__ float zsh;
    float z = (tid < NCHUNK) ? pz[b * NCHUNK + tid] : 0.f;
#pragma unroll
    for (int off = 1; off < 32; off <<= 1) z += __shfl_xor(z, off, 64);
    if (tid == 0) zsh = z;
    __syncthreads();
    const float invz = 1.0f / zsh;

#pragma unroll
    for (int i = 0; i < 2; i++) {
        int d = tid + i * 256;
        float mu = 0.f, m2 = 0.f;
#pragma unroll
        for (int c = 0; c < NCHUNK; c++) {
            mu += pmu[((long)b * NCHUNK + c) * D_ + d];
            m2 += pm2[((long)b * NCHUNK + c) * D_ + d];
        }
        mu *= invz;
        m2 *= invz;
        out[(long)b * (2 * D_) + d] = mu;
        out[(long)b * (2 * D_) + D_ + d] = sqrtf(fmaxf(m2 - mu * mu, 0.f) + 1e-6f);
    }
}

extern "C" void kernel_launch(void* const* d_in, const int* in_sizes, int n_in,
                              void* d_out, int out_size, void* d_ws, size_t ws_size,
                              hipStream_t stream) {
    const float* x  = (const float*)d_in[0];
    const float* W1 = (const float*)d_in[1];
    const float* b1 = (const float*)d_in[2];
    const float* W2 = (const float*)d_in[3];
    const float* b2 = (const float*)d_in[4];
    float* out = (float*)d_out;

    const int nblk = (B_ * T_) / CHUNK;                   // 2048
    float* ws = (float*)d_ws;
    float* pmu = ws;                                       // nblk*512 f
    float* pm2 = pmu + (long)nblk * D_;                    // nblk*512 f
    float* pz  = pm2 + (long)nblk * D_;                    // nblk f
    __hip_bfloat16* W1T = (__hip_bfloat16*)(pz + nblk);    // 65536 bf16

    prep_kernel<<<256, 256, 0, stream>>>(W1, W1T);
    fused_kernel<<<nblk, 256, 0, stream>>>(x, W1T, b1, W2, b2, pmu, pm2, pz);
    finalize_kernel<<<B_, 256, 0, stream>>>(pmu, pm2, pz, out);
}